// Round 1
// baseline (494.884 us; speedup 1.0000x reference)
//
#include <hip/hip_runtime.h>

// DenseRecurrentConsciousnessNet on MI355X (gfx950)
// B=65536, H=512, S=256, D=64.  Fused plan:
//   k_init : pack [W_read|W_write|W_content]^T -> bf16 Wt[576][512] in ws,
//            memory^T -> bf16 memT[64][256], biases -> bfull[576], zero sums.
//   k_main : one block per 32 rows. bf16 MFMA GEMM [32,512]@[512,576]
//            (A=query for n<512, content for n>=512), epilogue: biased logits
//            -> LDS, dual softmax, P@memory via MFMA, col-sum atomics.
//   k_final: EMA consolidation + age update (256x64).

typedef short short8 __attribute__((ext_vector_type(8)));
typedef float floatx4 __attribute__((ext_vector_type(4)));

#define H_DIM 512
#define BM 32
#define BK 32

// ws byte offsets
#define WS_WT    0          // bf16 [576][512]  = 589824 B
#define WS_MEMT  589824     // bf16 [64][256]   = 32768 B
#define WS_BFULL 622592     // f32  [576]       = 2304 B
#define WS_WSUM  624896     // f32  [256]       = 1024 B
#define WS_CSUM  625920     // f32  [64]        = 256 B

__device__ __forceinline__ unsigned short f2b(float f) {
  unsigned u = __float_as_uint(f);
  u += 0x7fffu + ((u >> 16) & 1u);          // round-to-nearest-even
  return (unsigned short)(u >> 16);
}
__device__ __forceinline__ float b2f(unsigned short h) {
  return __uint_as_float(((unsigned)h) << 16);
}

__global__ void drcn_init(const float* __restrict__ W_read, const float* __restrict__ W_write,
                          const float* __restrict__ W_content, const float* __restrict__ b_read,
                          const float* __restrict__ b_write, const float* __restrict__ b_content,
                          const float* __restrict__ memory,
                          unsigned short* __restrict__ Wt, unsigned short* __restrict__ memT,
                          float* __restrict__ bfull, float* __restrict__ w_sum,
                          float* __restrict__ c_sum) {
  int idx = blockIdx.x * 256 + threadIdx.x;
  if (idx < 294912) {                       // Wt[n][k] = W[k][n], bf16
    int n = idx >> 9, k = idx & 511;
    float v;
    if (n < 256)      v = W_read[k * 256 + n];
    else if (n < 512) v = W_write[k * 256 + (n - 256)];
    else              v = W_content[k * 64 + (n - 512)];
    Wt[idx] = f2b(v);
  } else if (idx < 311296) {                // memT[d][s] = memory[s][d], bf16
    int i = idx - 294912;
    int d = i >> 8, s = i & 255;
    memT[i] = f2b(memory[s * 64 + d]);
  } else if (idx < 311872) {                // packed bias [576]
    int n = idx - 311296;
    bfull[n] = (n < 256) ? b_read[n] : (n < 512 ? b_write[n - 256] : b_content[n - 512]);
  } else if (idx < 312192) {                // zero accumulators (ws is 0xAA-poisoned)
    int i = idx - 311872;
    if (i < 256) w_sum[i] = 0.0f; else c_sum[i - 256] = 0.0f;
  }
}

__global__ __launch_bounds__(256, 2) void drcn_main(
    const float* __restrict__ query, const float* __restrict__ content,
    const unsigned short* __restrict__ Wt, const float* __restrict__ bfull,
    const unsigned short* __restrict__ memT, float* __restrict__ w_sum,
    float* __restrict__ c_sum, float* __restrict__ out) {
  // LDS union: GEMM staging {wt[576][40] | qa[32][40] | ca[32][40]} = 51200 B
  //            epilogue    {lg[32][584] bf16 | cs[256] f32 | cp[64] f32} = 38656 B
  __shared__ __align__(16) char smem[51200];
  unsigned short* wt = (unsigned short*)smem;            // rows padded 32->40 elems (80 B)
  unsigned short* qa = (unsigned short*)(smem + 46080);
  unsigned short* ca = (unsigned short*)(smem + 48640);
  unsigned short* lg = (unsigned short*)smem;            // rows padded 576->584 (1168 B)
  float* cs = (float*)(smem + 37376);
  float* cp = (float*)(smem + 38400);

  const int t = threadIdx.x;
  const int wv = t >> 6;
  const int ln = t & 63;
  const int ln15 = ln & 15;
  const int quad = ln >> 4;
  const int m0 = blockIdx.x * BM;

  float bias[9];
  #pragma unroll
  for (int j = 0; j < 9; j++) bias[j] = bfull[(wv * 9 + j) * 16 + ln15];

  floatx4 acc[2][9];
  #pragma unroll
  for (int mt = 0; mt < 2; mt++)
    #pragma unroll
    for (int j = 0; j < 9; j++) {
      floatx4 z = {0.0f, 0.0f, 0.0f, 0.0f};
      acc[mt][j] = z;
    }

  for (int k0 = 0; k0 < H_DIM; k0 += BK) {
    __syncthreads();
    // stage weight tile: all 576 n-rows x 32 k, bf16, from L2-resident Wt
    #pragma unroll
    for (int j = 0; j < 9; j++) {
      int id = j * 256 + t;                 // 2304 16-B chunks
      int n = id >> 2, q = id & 3;
      uint4 v = *(const uint4*)(Wt + n * 512 + k0 + q * 8);
      *(uint4*)(wt + n * 40 + q * 8) = v;
    }
    // stage query/content rows with inline f32->bf16
    {
      int m = t >> 3, q = t & 7;
      const float4 fq = *(const float4*)(query + (size_t)(m0 + m) * H_DIM + k0 + q * 4);
      unsigned lo = (unsigned)f2b(fq.x) | ((unsigned)f2b(fq.y) << 16);
      unsigned hi = (unsigned)f2b(fq.z) | ((unsigned)f2b(fq.w) << 16);
      *(uint2*)(qa + m * 40 + q * 4) = make_uint2(lo, hi);
      const float4 fc = *(const float4*)(content + (size_t)(m0 + m) * H_DIM + k0 + q * 4);
      lo = (unsigned)f2b(fc.x) | ((unsigned)f2b(fc.y) << 16);
      hi = (unsigned)f2b(fc.z) | ((unsigned)f2b(fc.w) << 16);
      *(uint2*)(ca + m * 40 + q * 4) = make_uint2(lo, hi);
    }
    __syncthreads();

    short8 aq[2], ac[2];
    #pragma unroll
    for (int mt = 0; mt < 2; mt++) {
      aq[mt] = *(const short8*)(qa + (mt * 16 + ln15) * 40 + quad * 8);
      ac[mt] = *(const short8*)(ca + (mt * 16 + ln15) * 40 + quad * 8);
    }
    #pragma unroll
    for (int j = 0; j < 9; j++) {
      int nt = wv * 9 + j;
      short8 b = *(const short8*)(wt + (nt * 16 + ln15) * 40 + quad * 8);
      #pragma unroll
      for (int mt = 0; mt < 2; mt++) {
        short8 a = (nt >= 32) ? ac[mt] : aq[mt];   // content columns use content rows
        acc[mt][j] = __builtin_amdgcn_mfma_f32_16x16x32_bf16(a, b, acc[mt][j], 0, 0, 0);
      }
    }
  }
  __syncthreads();

  // dump biased logits to LDS (C/D layout: col=lane&15, row=quad*4+reg)
  #pragma unroll
  for (int j = 0; j < 9; j++) {
    int n = (wv * 9 + j) * 16 + ln15;
    #pragma unroll
    for (int mt = 0; mt < 2; mt++) {
      #pragma unroll
      for (int r = 0; r < 4; r++) {
        int row = mt * 16 + quad * 4 + r;
        lg[row * 584 + n] = f2b(acc[mt][j][r] + bias[j]);
      }
    }
  }
  cs[t] = 0.0f;
  if (t < 64) cp[t] = 0.0f;
  __syncthreads();

  const int r = t >> 3, c = t & 7;          // 8 threads per row
  unsigned short* lrow = lg + r * 584;

  // ---- read softmax: cols [0,256), normalized P written back in place ----
  {
    float v[32];
    #pragma unroll
    for (int ch = 0; ch < 4; ch++) {
      short8 u = *(const short8*)(lrow + c * 32 + ch * 8);
      #pragma unroll
      for (int e = 0; e < 8; e++) v[ch * 8 + e] = b2f((unsigned short)u[e]);
    }
    float mx = -3.0e38f;
    #pragma unroll
    for (int i = 0; i < 32; i++) mx = fmaxf(mx, v[i]);
    mx = fmaxf(mx, __shfl_xor(mx, 1));
    mx = fmaxf(mx, __shfl_xor(mx, 2));
    mx = fmaxf(mx, __shfl_xor(mx, 4));
    float sm = 0.0f;
    #pragma unroll
    for (int i = 0; i < 32; i++) { v[i] = __expf(v[i] - mx); sm += v[i]; }
    sm += __shfl_xor(sm, 1);
    sm += __shfl_xor(sm, 2);
    sm += __shfl_xor(sm, 4);
    float inv = 1.0f / sm;
    #pragma unroll
    for (int ch = 0; ch < 4; ch++) {
      short8 u;
      #pragma unroll
      for (int e = 0; e < 8; e++) u[e] = (short)f2b(v[ch * 8 + e] * inv);
      *(short8*)(lrow + c * 32 + ch * 8) = u;
    }
  }
  // ---- write softmax: cols [256,512), only column sums needed ----
  {
    float v[32];
    #pragma unroll
    for (int ch = 0; ch < 4; ch++) {
      short8 u = *(const short8*)(lrow + 256 + c * 32 + ch * 8);
      #pragma unroll
      for (int e = 0; e < 8; e++) v[ch * 8 + e] = b2f((unsigned short)u[e]);
    }
    float mx = -3.0e38f;
    #pragma unroll
    for (int i = 0; i < 32; i++) mx = fmaxf(mx, v[i]);
    mx = fmaxf(mx, __shfl_xor(mx, 1));
    mx = fmaxf(mx, __shfl_xor(mx, 2));
    mx = fmaxf(mx, __shfl_xor(mx, 4));
    float sm = 0.0f;
    #pragma unroll
    for (int i = 0; i < 32; i++) { v[i] = __expf(v[i] - mx); sm += v[i]; }
    sm += __shfl_xor(sm, 1);
    sm += __shfl_xor(sm, 2);
    sm += __shfl_xor(sm, 4);
    float inv = 1.0f / sm;
    #pragma unroll
    for (int i = 0; i < 32; i++) {          // reduce the wave's 8 rows
      float p = v[i] * inv;
      p += __shfl_xor(p, 8);
      p += __shfl_xor(p, 16);
      p += __shfl_xor(p, 32);
      v[i] = p;
    }
    if (ln < 8) {
      #pragma unroll
      for (int i = 0; i < 32; i++) atomicAdd(&cs[c * 32 + i], v[i]);
    }
  }
  // ---- processed-content partial sums: cols [512,576) ----
  {
    float v[8];
    short8 u = *(const short8*)(lrow + 512 + c * 8);
    #pragma unroll
    for (int e = 0; e < 8; e++) v[e] = b2f((unsigned short)u[e]);
    #pragma unroll
    for (int e = 0; e < 8; e++) {
      float p = v[e];
      p += __shfl_xor(p, 8);
      p += __shfl_xor(p, 16);
      p += __shfl_xor(p, 32);
      v[e] = p;
    }
    if (ln < 8) {
      #pragma unroll
      for (int e = 0; e < 8; e++) atomicAdd(&cp[c * 8 + e], v[e]);
    }
  }
  __syncthreads();

  // ---- PV: read_content = P @ memory; B-frags straight from L2-resident memT ----
  {
    int mt = wv & 1, nd0 = (wv >> 1) * 2;
    floatx4 ra[2];
    floatx4 z = {0.0f, 0.0f, 0.0f, 0.0f};
    ra[0] = z; ra[1] = z;
    #pragma unroll
    for (int ks = 0; ks < 8; ks++) {
      int s0 = ks * 32 + quad * 8;
      short8 a = *(const short8*)(lg + (mt * 16 + ln15) * 584 + s0);
      #pragma unroll
      for (int dt = 0; dt < 2; dt++) {
        short8 b = *(const short8*)(memT + ((nd0 + dt) * 16 + ln15) * 256 + s0);
        ra[dt] = __builtin_amdgcn_mfma_f32_16x16x32_bf16(a, b, ra[dt], 0, 0, 0);
      }
    }
    #pragma unroll
    for (int dt = 0; dt < 2; dt++)
      #pragma unroll
      for (int rr = 0; rr < 4; rr++) {
        int orow = m0 + mt * 16 + quad * 4 + rr;
        out[(size_t)orow * 64 + (nd0 + dt) * 16 + ln15] = ra[dt][rr];
      }
  }

  // block partials -> global accumulators
  atomicAdd(&w_sum[t], cs[t]);
  if (t < 64) atomicAdd(&c_sum[t], cp[t]);
}

__global__ void drcn_final(const float* __restrict__ memory, const float* __restrict__ age,
                           const float* __restrict__ w_sum, const float* __restrict__ c_sum,
                           float* __restrict__ out_mem, float* __restrict__ out_age) {
  int idx = blockIdx.x * 256 + threadIdx.x;   // 16384 = 256 slots * 64
  int s = idx >> 6, d = idx & 63;
  float wm = w_sum[s] * (1.0f / 65536.0f);
  bool act = wm > 0.01f;
  float cons = 1.0f / (1.0f + __expf(-age[s] * 0.1f));
  float alpha = act ? wm * cons : 0.0f;
  float cm = c_sum[d] * (1.0f / 65536.0f);
  out_mem[idx] = (1.0f - alpha) * memory[idx] + alpha * cm;
  if (d == 0) out_age[s] = age[s] + (act ? 1.0f : 0.0f);
}

extern "C" void kernel_launch(void* const* d_in, const int* in_sizes, int n_in,
                              void* d_out, int out_size, void* d_ws, size_t ws_size,
                              hipStream_t stream) {
  (void)in_sizes; (void)n_in; (void)out_size; (void)ws_size;
  const float* query     = (const float*)d_in[0];
  const float* content   = (const float*)d_in[1];
  const float* memory    = (const float*)d_in[2];
  const float* mem_age   = (const float*)d_in[3];
  const float* W_read    = (const float*)d_in[4];
  const float* b_read    = (const float*)d_in[5];
  const float* W_write   = (const float*)d_in[6];
  const float* b_write   = (const float*)d_in[7];
  const float* W_content = (const float*)d_in[8];
  const float* b_content = (const float*)d_in[9];
  float* out = (float*)d_out;
  char* ws = (char*)d_ws;
  unsigned short* Wt   = (unsigned short*)(ws + WS_WT);
  unsigned short* memT = (unsigned short*)(ws + WS_MEMT);
  float* bfull = (float*)(ws + WS_BFULL);
  float* w_sum = (float*)(ws + WS_WSUM);
  float* c_sum = (float*)(ws + WS_CSUM);

  drcn_init<<<1220, 256, 0, stream>>>(W_read, W_write, W_content, b_read, b_write,
                                      b_content, memory, Wt, memT, bfull, w_sum, c_sum);
  drcn_main<<<2048, 256, 0, stream>>>(query, content, Wt, bfull, memT, w_sum, c_sum, out);
  drcn_final<<<64, 256, 0, stream>>>(memory, mem_age, w_sum, c_sum,
                                     out + 4194304, out + 4210688);
}

// Round 2
// 442.091 us; speedup vs baseline: 1.1194x; 1.1194x over previous
//
#include <hip/hip_runtime.h>
#include <hip/hip_bf16.h>

// DenseRecurrentConsciousnessNet on MI355X (gfx950)
// B=65536, H=512, S=256, D=64.
// R2: barrier-free K-loop. Wave-private weight staging via global_load_lds
// (double-buffered, per-wave s_waitcnt vmcnt(0) instead of __syncthreads),
// A (query/content) direct global->VGPR with 1-iter register prefetch and
// packed bf16 conversion. Epilogue unchanged from R1 (passed, absmax 0.0117).

typedef short short8 __attribute__((ext_vector_type(8)));
typedef float floatx4 __attribute__((ext_vector_type(4)));

#define H_DIM 512
#define BM 32

// ws byte offsets
#define WS_WT    0          // bf16 [576][512]  = 589824 B
#define WS_MEMT  589824     // bf16 [64][256]   = 32768 B
#define WS_BFULL 622592     // f32  [576]       = 2304 B
#define WS_WSUM  624896     // f32  [256]       = 1024 B
#define WS_CSUM  625920     // f32  [64]        = 256 B

__device__ __forceinline__ unsigned short f2b(float f) {
  unsigned u = __float_as_uint(f);
  u += 0x7fffu + ((u >> 16) & 1u);          // round-to-nearest-even
  return (unsigned short)(u >> 16);
}
__device__ __forceinline__ float b2f(unsigned short h) {
  return __uint_as_float(((unsigned)h) << 16);
}
__device__ __forceinline__ unsigned cvt2(float x, float y) {
  union { __hip_bfloat162 h; unsigned u; } c;
  c.h = __float22bfloat162_rn(make_float2(x, y));
  return c.u;
}
// async 16B-per-lane global->LDS (lds dest = wave-uniform base + lane*16)
__device__ __forceinline__ void async16(const void* g, void* l) {
  __builtin_amdgcn_global_load_lds(
      (const __attribute__((address_space(1))) unsigned int*)g,
      (__attribute__((address_space(3))) unsigned int*)l, 16, 0, 0);
}

__global__ void drcn_init(const float* __restrict__ W_read, const float* __restrict__ W_write,
                          const float* __restrict__ W_content, const float* __restrict__ b_read,
                          const float* __restrict__ b_write, const float* __restrict__ b_content,
                          const float* __restrict__ memory,
                          unsigned short* __restrict__ Wt, unsigned short* __restrict__ memT,
                          float* __restrict__ bfull, float* __restrict__ w_sum,
                          float* __restrict__ c_sum) {
  int idx = blockIdx.x * 256 + threadIdx.x;
  if (idx < 294912) {                       // Wt[n][k] = W[k][n], bf16
    int n = idx >> 9, k = idx & 511;
    float v;
    if (n < 256)      v = W_read[k * 256 + n];
    else if (n < 512) v = W_write[k * 256 + (n - 256)];
    else              v = W_content[k * 64 + (n - 512)];
    Wt[idx] = f2b(v);
  } else if (idx < 311296) {                // memT[d][s] = memory[s][d], bf16
    int i = idx - 294912;
    int d = i >> 8, s = i & 255;
    memT[i] = f2b(memory[s * 64 + d]);
  } else if (idx < 311872) {                // packed bias [576]
    int n = idx - 311296;
    bfull[n] = (n < 256) ? b_read[n] : (n < 512 ? b_write[n - 256] : b_content[n - 512]);
  } else if (idx < 312192) {                // zero accumulators
    int i = idx - 311872;
    if (i < 256) w_sum[i] = 0.0f; else c_sum[i - 256] = 0.0f;
  }
}

__global__ __launch_bounds__(256, 2) void drcn_main(
    const float* __restrict__ query, const float* __restrict__ content,
    const unsigned short* __restrict__ Wt, const float* __restrict__ bfull,
    const unsigned short* __restrict__ memT, float* __restrict__ w_sum,
    float* __restrict__ c_sum, float* __restrict__ out) {
  // staging: 2 buffers x 4 waves x 9216 B (wave-private [144][32] bf16 tiles)
  // epilogue union: lg[32][584] bf16 (37376) | cs[256] f32 | cp[64] f32
  __shared__ __align__(16) char smem[73728];
  unsigned short* lg = (unsigned short*)smem;
  float* cs = (float*)(smem + 37376);
  float* cp = (float*)(smem + 38400);

  const int t = threadIdx.x;
  const int wv = t >> 6;
  const int ln = t & 63;
  const int ln15 = ln & 15;
  const int quad = ln >> 4;
  const int m0 = blockIdx.x * BM;

  // per-lane global source for this wave's wt chunks:
  // chunk j, lane l covers row (wv*144 + j*16 + l/4), kpart (l&3)*8 elems
  const char* wsrc = (const char*)Wt +
      (size_t)(((wv * 144 + (ln >> 2)) * 512 + (ln & 3) * 8) * 2);
  char* wbase = smem + wv * 9216;           // wave-uniform LDS base (buf 0)

  const float* qb[2]; const float* cb[2];
  #pragma unroll
  for (int mt = 0; mt < 2; mt++) {
    qb[mt] = query   + (size_t)(m0 + mt * 16 + ln15) * H_DIM + quad * 8;
    cb[mt] = content + (size_t)(m0 + mt * 16 + ln15) * H_DIM + quad * 8;
  }

  float bias[9];
  #pragma unroll
  for (int j = 0; j < 9; j++) bias[j] = bfull[(wv * 9 + j) * 16 + ln15];

  floatx4 acc[2][9];
  #pragma unroll
  for (int mt = 0; mt < 2; mt++)
    #pragma unroll
    for (int j = 0; j < 9; j++) {
      floatx4 z = {0.0f, 0.0f, 0.0f, 0.0f};
      acc[mt][j] = z;
    }

  // ---- preissue iter 0: A f32 prefetch regs first, then wt chunks ----
  float4 pq[2][2], pc[2][2];
  #pragma unroll
  for (int mt = 0; mt < 2; mt++) {
    pq[mt][0] = *(const float4*)(qb[mt]);
    pq[mt][1] = *(const float4*)(qb[mt] + 4);
    pc[mt][0] = *(const float4*)(cb[mt]);
    pc[mt][1] = *(const float4*)(cb[mt] + 4);
  }
  #pragma unroll
  for (int j = 0; j < 9; j++)
    async16(wsrc + j * 16384, wbase + j * 1024);

  // ---- barrier-free K-loop (16 iters of BK=32) ----
  #pragma unroll 2
  for (int it = 0; it < 16; ++it) {
    // build bf16 A-frags from prefetch regs (compiler inserts vmcnt wait,
    // leaving the 9 newer wt loads in flight)
    short8 aq[2], ac[2];
    #pragma unroll
    for (int mt = 0; mt < 2; mt++) {
      unsigned* p = (unsigned*)&aq[mt];
      p[0] = cvt2(pq[mt][0].x, pq[mt][0].y);
      p[1] = cvt2(pq[mt][0].z, pq[mt][0].w);
      p[2] = cvt2(pq[mt][1].x, pq[mt][1].y);
      p[3] = cvt2(pq[mt][1].z, pq[mt][1].w);
      unsigned* q = (unsigned*)&ac[mt];
      q[0] = cvt2(pc[mt][0].x, pc[mt][0].y);
      q[1] = cvt2(pc[mt][0].z, pc[mt][0].w);
      q[2] = cvt2(pc[mt][1].x, pc[mt][1].y);
      q[3] = cvt2(pc[mt][1].z, pc[mt][1].w);
    }
    // drain this iter's wt (issued one iteration ago) — per-wave, no barrier
    asm volatile("s_waitcnt vmcnt(0)" ::: "memory");

    if (it < 15) {
      const int k1 = (it + 1) * 32;
      #pragma unroll
      for (int mt = 0; mt < 2; mt++) {      // A(it+1) first (oldest)
        pq[mt][0] = *(const float4*)(qb[mt] + k1);
        pq[mt][1] = *(const float4*)(qb[mt] + k1 + 4);
        pc[mt][0] = *(const float4*)(cb[mt] + k1);
        pc[mt][1] = *(const float4*)(cb[mt] + k1 + 4);
      }
      const char* ws2 = wsrc + (size_t)(it + 1) * 64;   // +32 elems * 2B
      char* wd = smem + ((it + 1) & 1) * 36864 + wv * 9216;
      #pragma unroll
      for (int j = 0; j < 9; j++)           // wt(it+1) second (newest)
        async16(ws2 + j * 16384, wd + j * 1024);
    }

    const char* rb = smem + (it & 1) * 36864 + wv * 9216;
    #pragma unroll
    for (int j = 0; j < 9; j++) {
      short8 b = *(const short8*)(rb + j * 1024 + ln15 * 64 + quad * 16);
      const int nt = wv * 9 + j;
      #pragma unroll
      for (int mt = 0; mt < 2; mt++) {
        short8 a = (nt >= 32) ? ac[mt] : aq[mt];
        acc[mt][j] = __builtin_amdgcn_mfma_f32_16x16x32_bf16(a, b, acc[mt][j], 0, 0, 0);
      }
    }
  }
  __syncthreads();   // all waves done with staging regions before lg overwrite

  // ---- dump biased logits to LDS (C/D layout: col=lane&15, row=quad*4+reg) ----
  #pragma unroll
  for (int j = 0; j < 9; j++) {
    int n = (wv * 9 + j) * 16 + ln15;
    #pragma unroll
    for (int mt = 0; mt < 2; mt++) {
      #pragma unroll
      for (int r = 0; r < 4; r++) {
        int row = mt * 16 + quad * 4 + r;
        lg[row * 584 + n] = f2b(acc[mt][j][r] + bias[j]);
      }
    }
  }
  cs[t] = 0.0f;
  if (t < 64) cp[t] = 0.0f;
  __syncthreads();

  const int r = t >> 3, c = t & 7;          // 8 threads per row
  unsigned short* lrow = lg + r * 584;

  // ---- read softmax: cols [0,256), normalized P written back in place ----
  {
    float v[32];
    #pragma unroll
    for (int ch = 0; ch < 4; ch++) {
      short8 u = *(const short8*)(lrow + c * 32 + ch * 8);
      #pragma unroll
      for (int e = 0; e < 8; e++) v[ch * 8 + e] = b2f((unsigned short)u[e]);
    }
    float mx = -3.0e38f;
    #pragma unroll
    for (int i = 0; i < 32; i++) mx = fmaxf(mx, v[i]);
    mx = fmaxf(mx, __shfl_xor(mx, 1));
    mx = fmaxf(mx, __shfl_xor(mx, 2));
    mx = fmaxf(mx, __shfl_xor(mx, 4));
    float sm = 0.0f;
    #pragma unroll
    for (int i = 0; i < 32; i++) { v[i] = __expf(v[i] - mx); sm += v[i]; }
    sm += __shfl_xor(sm, 1);
    sm += __shfl_xor(sm, 2);
    sm += __shfl_xor(sm, 4);
    float inv = 1.0f / sm;
    #pragma unroll
    for (int ch = 0; ch < 4; ch++) {
      short8 u;
      #pragma unroll
      for (int e = 0; e < 8; e++) u[e] = (short)f2b(v[ch * 8 + e] * inv);
      *(short8*)(lrow + c * 32 + ch * 8) = u;
    }
  }
  // ---- write softmax: cols [256,512), only column sums needed ----
  {
    float v[32];
    #pragma unroll
    for (int ch = 0; ch < 4; ch++) {
      short8 u = *(const short8*)(lrow + 256 + c * 32 + ch * 8);
      #pragma unroll
      for (int e = 0; e < 8; e++) v[ch * 8 + e] = b2f((unsigned short)u[e]);
    }
    float mx = -3.0e38f;
    #pragma unroll
    for (int i = 0; i < 32; i++) mx = fmaxf(mx, v[i]);
    mx = fmaxf(mx, __shfl_xor(mx, 1));
    mx = fmaxf(mx, __shfl_xor(mx, 2));
    mx = fmaxf(mx, __shfl_xor(mx, 4));
    float sm = 0.0f;
    #pragma unroll
    for (int i = 0; i < 32; i++) { v[i] = __expf(v[i] - mx); sm += v[i]; }
    sm += __shfl_xor(sm, 1);
    sm += __shfl_xor(sm, 2);
    sm += __shfl_xor(sm, 4);
    float inv = 1.0f / sm;
    #pragma unroll
    for (int i = 0; i < 32; i++) {          // reduce the wave's 8 rows
      float p = v[i] * inv;
      p += __shfl_xor(p, 8);
      p += __shfl_xor(p, 16);
      p += __shfl_xor(p, 32);
      v[i] = p;
    }
    if (ln < 8) {
      #pragma unroll
      for (int i = 0; i < 32; i++) atomicAdd(&cs[c * 32 + i], v[i]);
    }
  }
  // ---- processed-content partial sums: cols [512,576) ----
  {
    float v[8];
    short8 u = *(const short8*)(lrow + 512 + c * 8);
    #pragma unroll
    for (int e = 0; e < 8; e++) v[e] = b2f((unsigned short)u[e]);
    #pragma unroll
    for (int e = 0; e < 8; e++) {
      float p = v[e];
      p += __shfl_xor(p, 8);
      p += __shfl_xor(p, 16);
      p += __shfl_xor(p, 32);
      v[e] = p;
    }
    if (ln < 8) {
      #pragma unroll
      for (int e = 0; e < 8; e++) atomicAdd(&cp[c * 8 + e], v[e]);
    }
  }
  __syncthreads();

  // ---- PV: read_content = P @ memory; B-frags from L2-resident memT ----
  {
    int mt = wv & 1, nd0 = (wv >> 1) * 2;
    floatx4 ra[2];
    floatx4 z = {0.0f, 0.0f, 0.0f, 0.0f};
    ra[0] = z; ra[1] = z;
    #pragma unroll
    for (int ks = 0; ks < 8; ks++) {
      int s0 = ks * 32 + quad * 8;
      short8 a = *(const short8*)(lg + (mt * 16 + ln15) * 584 + s0);
      #pragma unroll
      for (int dt = 0; dt < 2; dt++) {
        short8 b = *(const short8*)(memT + ((nd0 + dt) * 16 + ln15) * 256 + s0);
        ra[dt] = __builtin_amdgcn_mfma_f32_16x16x32_bf16(a, b, ra[dt], 0, 0, 0);
      }
    }
    #pragma unroll
    for (int dt = 0; dt < 2; dt++)
      #pragma unroll
      for (int rr = 0; rr < 4; rr++) {
        int orow = m0 + mt * 16 + quad * 4 + rr;
        out[(size_t)orow * 64 + (nd0 + dt) * 16 + ln15] = ra[dt][rr];
      }
  }

  // block partials -> global accumulators
  atomicAdd(&w_sum[t], cs[t]);
  if (t < 64) atomicAdd(&c_sum[t], cp[t]);
}

__global__ void drcn_final(const float* __restrict__ memory, const float* __restrict__ age,
                           const float* __restrict__ w_sum, const float* __restrict__ c_sum,
                           float* __restrict__ out_mem, float* __restrict__ out_age) {
  int idx = blockIdx.x * 256 + threadIdx.x;   // 16384 = 256 slots * 64
  int s = idx >> 6, d = idx & 63;
  float wm = w_sum[s] * (1.0f / 65536.0f);
  bool act = wm > 0.01f;
  float cons = 1.0f / (1.0f + __expf(-age[s] * 0.1f));
  float alpha = act ? wm * cons : 0.0f;
  float cm = c_sum[d] * (1.0f / 65536.0f);
  out_mem[idx] = (1.0f - alpha) * memory[idx] + alpha * cm;
  if (d == 0) out_age[s] = age[s] + (act ? 1.0f : 0.0f);
}

extern "C" void kernel_launch(void* const* d_in, const int* in_sizes, int n_in,
                              void* d_out, int out_size, void* d_ws, size_t ws_size,
                              hipStream_t stream) {
  (void)in_sizes; (void)n_in; (void)out_size; (void)ws_size;
  const float* query     = (const float*)d_in[0];
  const float* content   = (const float*)d_in[1];
  const float* memory    = (const float*)d_in[2];
  const float* mem_age   = (const float*)d_in[3];
  const float* W_read    = (const float*)d_in[4];
  const float* b_read    = (const float*)d_in[5];
  const float* W_write   = (const float*)d_in[6];
  const float* b_write   = (const float*)d_in[7];
  const float* W_content = (const float*)d_in[8];
  const float* b_content = (const float*)d_in[9];
  float* out = (float*)d_out;
  char* ws = (char*)d_ws;
  unsigned short* Wt   = (unsigned short*)(ws + WS_WT);
  unsigned short* memT = (unsigned short*)(ws + WS_MEMT);
  float* bfull = (float*)(ws + WS_BFULL);
  float* w_sum = (float*)(ws + WS_WSUM);
  float* c_sum = (float*)(ws + WS_CSUM);

  drcn_init<<<1220, 256, 0, stream>>>(W_read, W_write, W_content, b_read, b_write,
                                      b_content, memory, Wt, memT, bfull, w_sum, c_sum);
  drcn_main<<<2048, 256, 0, stream>>>(query, content, Wt, bfull, memT, w_sum, c_sum, out);
  drcn_final<<<64, 256, 0, stream>>>(memory, mem_age, w_sum, c_sum,
                                     out + 4194304, out + 4210688);
}